// Round 4
// baseline (322.193 us; speedup 1.0000x reference)
//
#include <hip/hip_runtime.h>
#include <math.h>

// NT-Xent (SimCLR) loss. B=4096, D=256, T=0.5.
// R4: denom is latency-bound, not BW/MFMA-bound (R2≈R3 proved LDS staging
// neutral). Delete LDS staging entirely; load A and B MFMA fragments direct
// from L2 (zbF 4 MB = L2-resident, fragment-native layout so every load is a
// coalesced 1 KB global_load_dwordx4). Buy occupancy instead:
// __launch_bounds__(256,5) -> <=102 VGPR (natural alloc is 96) -> 5 blocks/CU
// = 5 waves/SIMD, ~2.5x the latency hiding of R2/R3.
//   zbF layout: rg = row>>4, ks = k>>5:
//     offset_shorts = rg*4096 + ks*512 + ((k>>3)&3)*128 + (row&15)*8 + (k&7)
// Rows scaled by sqrt(2/ln2): acc = 2*sim/ln2 -> epilogue exp2(acc) (v_exp,
// no mul). posv holds 2*sim/ln2; reduce weight = 2*ln2.
// T5 s_setprio around MFMA clusters. Only 2 KB LDS (reduction buffer).

#define NROWS 8192
#define NHALF 4096
#define DIM   256
#define BM    128
#define BN    128
#define NCB   (NROWS / BN)          // 64 row/col blocks
#define NTRI  (NCB * (NCB + 1) / 2) // 2080 triangle tiles

typedef __attribute__((ext_vector_type(8))) short bf16x8;
typedef __attribute__((ext_vector_type(4))) float f32x4;

static __device__ __forceinline__ unsigned short f2bf(float x) {
  unsigned int u = __float_as_uint(x);
  unsigned int r = (u + 0x7FFFu + ((u >> 16) & 1u)) >> 16;
  return (unsigned short)r;
}

// ---------------- normalize -> fragment-native layout (also zeroes out[0])
__global__ __launch_bounds__(256) void normalize_kernel(
    const float* __restrict__ emb_i, const float* __restrict__ emb_j,
    unsigned short* __restrict__ zbF, float* __restrict__ out) {
  __shared__ unsigned short tile[16 * DIM];  // 8 KB
  if (blockIdx.x == 0 && threadIdx.x == 0) out[0] = 0.f;
  const int w = threadIdx.x >> 6, lane = threadIdx.x & 63;
  const int rg = blockIdx.x;
  #pragma unroll
  for (int rr = 0; rr < 4; ++rr) {
    const int m16 = w * 4 + rr;
    const int row = rg * 16 + m16;
    const float* src = (row < NHALF) ? (emb_i + (size_t)row * DIM)
                                     : (emb_j + (size_t)(row - NHALF) * DIM);
    float4 v = ((const float4*)src)[lane];
    float ss = v.x * v.x + v.y * v.y + v.z * v.z + v.w * v.w;
    #pragma unroll
    for (int off = 32; off; off >>= 1) ss += __shfl_down(ss, off, 64);
    float total = __shfl(ss, 0, 64);
    // sqrt(2/ln2): acc = 2*sim/ln2, so epilogue is exp2(acc) directly.
    float inv = 1.69870077f / fmaxf(sqrtf(total), 1e-12f);
    ushort4 o;
    o.x = f2bf(v.x * inv); o.y = f2bf(v.y * inv);
    o.z = f2bf(v.z * inv); o.w = f2bf(v.w * inv);
    // k = lane*4 -> ks = lane>>3, quad = (lane>>1)&3, j = (lane&1)*4
    const int ks = lane >> 3, quad = (lane >> 1) & 3, jj = (lane & 1) * 4;
    *(ushort4*)&tile[ks * 512 + (quad * 16 + m16) * 8 + jj] = o;
  }
  __syncthreads();
  uint4* dst = (uint4*)(zbF + (size_t)rg * (16 * DIM));
  const uint4* srcT = (const uint4*)tile;
  dst[threadIdx.x] = srcT[threadIdx.x];
  dst[256 + threadIdx.x] = srcT[256 + threadIdx.x];
}

// ------------------------------------------------ MFMA GEMM + exp + sums
__global__ __launch_bounds__(256, 5) void denom_kernel(
    const unsigned short* __restrict__ zbF, float* __restrict__ denomP,
    float* __restrict__ posv) {
  __shared__ float red[512];  // 2 KB: [0,256) rowsums, [256,512) colsums

  // decode triangle tile id -> (bx, by), bx <= by
  int t = blockIdx.x;
  int by = (int)((sqrtf(8.0f * (float)t + 1.0f) - 1.0f) * 0.5f);
  while ((by + 1) * (by + 2) / 2 <= t) ++by;
  while (by * (by + 1) / 2 > t) --by;
  int bx = t - by * (by + 1) / 2;

  const int tid = threadIdx.x;
  const int w = tid >> 6;
  const int lane = tid & 63;
  const int wr = w >> 1, wc = w & 1;  // 2x2 wave grid, 64x64 each
  const int quad = lane >> 4;
  const int m16 = lane & 15;
  const int row0 = bx * BM;
  const int col0 = by * BN;

  // fragment base pointers: rg = bx*8 + wr*4 + i (A), by*8 + wc*4 + j (B);
  // lane's 16 B fragment sits at +lane*8 shorts; k-slice step = 512 shorts.
  const unsigned short* pA[4];
  const unsigned short* pB[4];
  #pragma unroll
  for (int i = 0; i < 4; ++i) {
    pA[i] = zbF + (size_t)(bx * 8 + wr * 4 + i) * 4096 + lane * 8;
    pB[i] = zbF + (size_t)(by * 8 + wc * 4 + i) * 4096 + lane * 8;
  }

  f32x4 acc[4][4];
  #pragma unroll
  for (int i = 0; i < 4; ++i)
    #pragma unroll
    for (int j = 0; j < 4; ++j) {
      f32x4 z4 = {0.f, 0.f, 0.f, 0.f};
      acc[i][j] = z4;
    }

#define LOADAB(A, B, ks)                                          \
  do {                                                            \
    _Pragma("unroll") for (int i = 0; i < 4; ++i) {               \
      A[i] = *(const bf16x8*)(pA[i] + (ks) * 512);                \
      B[i] = *(const bf16x8*)(pB[i] + (ks) * 512);                \
    }                                                             \
  } while (0)

#define MFMA16(A, B)                                              \
  do {                                                            \
    __builtin_amdgcn_s_setprio(1);                                \
    _Pragma("unroll") for (int i = 0; i < 4; ++i)                 \
        _Pragma("unroll") for (int j = 0; j < 4; ++j)             \
            acc[i][j] = __builtin_amdgcn_mfma_f32_16x16x32_bf16(  \
                A[i], B[j], acc[i][j], 0, 0, 0);                  \
    __builtin_amdgcn_s_setprio(0);                                \
  } while (0)

  bf16x8 aE[4], bE[4], aO[4], bO[4];
  LOADAB(aE, bE, 0);
  LOADAB(aO, bO, 1);
  #pragma unroll
  for (int k2 = 0; k2 < 4; ++k2) {
    MFMA16(aE, bE);
    if (k2 < 3) LOADAB(aE, bE, 2 * k2 + 2);
    MFMA16(aO, bO);
    if (k2 < 3) LOADAB(aO, bO, 2 * k2 + 3);
  }
#undef LOADAB
#undef MFMA16

  // pos extraction: only tiles with col0 == row0 + NHALF hold pair elements.
  // acc = 2*sim/ln2; reduce applies weight 2*ln2.
  if (col0 - row0 == NHALF) {
    #pragma unroll
    for (int i = 0; i < 4; ++i)
      #pragma unroll
      for (int j = 0; j < 4; ++j) {
        int gcol = col0 + wc * 64 + j * 16 + m16;
        #pragma unroll
        for (int r = 0; r < 4; ++r) {
          int grow = row0 + wr * 64 + i * 16 + quad * 4 + r;
          if (gcol - grow == NHALF) posv[grow] = acc[i][j][r];
        }
      }
  }

  // Epilogue: e = exp2(acc) = exp(2*sim). Diagonal tiles (bx==by, 64 of
  // 2080) pay the grow==gcol compare; off-diagonal tiles skip it.
  float rs[4][4];
  float cs[4] = {0.f, 0.f, 0.f, 0.f};
  #pragma unroll
  for (int i = 0; i < 4; ++i)
    #pragma unroll
    for (int r = 0; r < 4; ++r) rs[i][r] = 0.f;

  if (bx != by) {
    #pragma unroll
    for (int i = 0; i < 4; ++i)
      #pragma unroll
      for (int j = 0; j < 4; ++j)
        #pragma unroll
        for (int r = 0; r < 4; ++r) {
          float e = __builtin_amdgcn_exp2f(acc[i][j][r]);
          rs[i][r] += e;
          cs[j] += e;
        }
  } else {
    #pragma unroll
    for (int i = 0; i < 4; ++i)
      #pragma unroll
      for (int j = 0; j < 4; ++j) {
        int gcol = col0 + wc * 64 + j * 16 + m16;
        #pragma unroll
        for (int r = 0; r < 4; ++r) {
          int grow = row0 + wr * 64 + i * 16 + quad * 4 + r;
          float e =
              (grow == gcol) ? 0.f : __builtin_amdgcn_exp2f(acc[i][j][r]);
          rs[i][r] += e;
          cs[j] += e;
        }
      }
  }

  // rowsum: reduce across the 16 column lanes (same quad)
  #pragma unroll
  for (int i = 0; i < 4; ++i)
    #pragma unroll
    for (int r = 0; r < 4; ++r) {
      float v = rs[i][r];
      v += __shfl_xor(v, 1, 16);
      v += __shfl_xor(v, 2, 16);
      v += __shfl_xor(v, 4, 16);
      v += __shfl_xor(v, 8, 16);
      if (m16 == 0) red[wc * 128 + wr * 64 + i * 16 + quad * 4 + r] = v;
    }
  // colsum: reduce across the 4 quads
  #pragma unroll
  for (int j = 0; j < 4; ++j) {
    float v = cs[j];
    v += __shfl_xor(v, 16, 64);
    v += __shfl_xor(v, 32, 64);
    if (quad == 0) red[256 + wr * 128 + wc * 64 + j * 16 + m16] = v;
  }
  __syncthreads();

  if (tid < 128) {
    denomP[(size_t)by * NROWS + row0 + tid] = red[tid] + red[128 + tid];
  } else if (bx != by) {
    int c = tid - 128;
    denomP[(size_t)bx * NROWS + col0 + c] = red[256 + c] + red[384 + c];
  }
}

// -------------------- denom slots -> -log; + 2*ln2*pos'; atomic into loss
__global__ __launch_bounds__(256) void reduce_kernel(
    const float* __restrict__ denomP, const float* __restrict__ posv,
    float* __restrict__ out) {
  int tid = threadIdx.x;
  int r = blockIdx.x * 256 + tid;  // 32 blocks cover 8192 rows
  float s = 0.f;
  #pragma unroll 8
  for (int b = 0; b < NCB; ++b) s += denomP[(size_t)b * NROWS + r];
  float v = -logf(s);
  // posv = 2*sim/ln2; need 4*sim (covers rows r and r+NHALF) = 2*ln2*posv
  if (r < NHALF) v += 1.38629436112f * posv[r];
  #pragma unroll
  for (int off = 32; off; off >>= 1) v += __shfl_down(v, off, 64);
  __shared__ float s4[4];
  if ((tid & 63) == 0) s4[tid >> 6] = v;
  __syncthreads();
  if (tid == 0)
    atomicAdd(out, (s4[0] + s4[1] + s4[2] + s4[3]) * (1.0f / 8192.0f));
}

extern "C" void kernel_launch(void* const* d_in, const int* in_sizes, int n_in,
                              void* d_out, int out_size, void* d_ws,
                              size_t ws_size, hipStream_t stream) {
  const float* emb_i = (const float*)d_in[0];
  const float* emb_j = (const float*)d_in[1];
  unsigned short* zbF = (unsigned short*)d_ws;           // 4 MB (frag layout)
  float* denomP = (float*)(zbF + (size_t)NROWS * DIM);   // 64*8192 f32 (2 MB)
  float* posv = denomP + (size_t)NCB * NROWS;            // 4096 f32
  float* out = (float*)d_out;

  normalize_kernel<<<NROWS / 16, 256, 0, stream>>>(emb_i, emb_j, zbF, out);
  denom_kernel<<<NTRI, 256, 0, stream>>>(zbF, denomP, posv);
  reduce_kernel<<<NROWS / 256, 256, 0, stream>>>(denomP, posv, out);
}

// Round 5
// 94.551 us; speedup vs baseline: 3.4076x; 3.4076x over previous
//
#include <hip/hip_runtime.h>
#include <math.h>

// NT-Xent (SimCLR) loss. B=4096, D=256, T=0.5.
// R5: denom is latency-bound (R1-R3: traffic varied 2x, perf flat; busy ~35%).
// Occupancy was reg-capped: 96 arch VGPR + 64 AGPR acc = 160 total (unified
// file!) -> 3 waves/SIMD. R4's (256,5) forced spills (acc -> scratch, 1.2 GB).
// Fix: keep data-in-flight OUT of registers -- LDS double-buffered staging via
// global_load_lds (frag-native layout, linear dest, conflict-free b128 reads).
// Budget: 64 acc + ~8x4 frags + addr ~ 115 total -> (256,4) = 4 blocks/CU =
// 16 waves/CU, LDS 34 KB x 4 = 136 KB. One barrier per K=32 stage, stage k+1
// issued before compute k. Bijective XCD swizzle on triangle index (2080%8==0).
//   zbF layout: rg = row>>4, ks = k>>5:
//     offset_shorts = rg*4096 + ks*512 + ((k>>3)&3)*128 + (row&15)*8 + (k&7)
// Rows scaled by sqrt(2/ln2): acc = 2*sim/ln2 -> epilogue exp2(acc);
// posv holds 2*sim/ln2; reduce weight = 2*ln2.

#define NROWS 8192
#define NHALF 4096
#define DIM   256
#define BM    128
#define BN    128
#define NCB   (NROWS / BN)          // 64 row/col blocks
#define NTRI  (NCB * (NCB + 1) / 2) // 2080 triangle tiles

typedef __attribute__((ext_vector_type(8))) short bf16x8;
typedef __attribute__((ext_vector_type(4))) float f32x4;

static __device__ __forceinline__ unsigned short f2bf(float x) {
  unsigned int u = __float_as_uint(x);
  unsigned int r = (u + 0x7FFFu + ((u >> 16) & 1u)) >> 16;
  return (unsigned short)r;
}

// ---------------- normalize -> fragment-native layout (also zeroes out[0])
__global__ __launch_bounds__(256) void normalize_kernel(
    const float* __restrict__ emb_i, const float* __restrict__ emb_j,
    unsigned short* __restrict__ zbF, float* __restrict__ out) {
  __shared__ unsigned short tile[16 * DIM];  // 8 KB
  if (blockIdx.x == 0 && threadIdx.x == 0) out[0] = 0.f;
  const int w = threadIdx.x >> 6, lane = threadIdx.x & 63;
  const int rg = blockIdx.x;
  #pragma unroll
  for (int rr = 0; rr < 4; ++rr) {
    const int m16 = w * 4 + rr;
    const int row = rg * 16 + m16;
    const float* src = (row < NHALF) ? (emb_i + (size_t)row * DIM)
                                     : (emb_j + (size_t)(row - NHALF) * DIM);
    float4 v = ((const float4*)src)[lane];
    float ss = v.x * v.x + v.y * v.y + v.z * v.z + v.w * v.w;
    #pragma unroll
    for (int off = 32; off; off >>= 1) ss += __shfl_down(ss, off, 64);
    float total = __shfl(ss, 0, 64);
    // sqrt(2/ln2): acc = 2*sim/ln2, so epilogue is exp2(acc) directly.
    float inv = 1.69870077f / fmaxf(sqrtf(total), 1e-12f);
    ushort4 o;
    o.x = f2bf(v.x * inv); o.y = f2bf(v.y * inv);
    o.z = f2bf(v.z * inv); o.w = f2bf(v.w * inv);
    // k = lane*4 -> ks = lane>>3, quad = (lane>>1)&3, j = (lane&1)*4
    const int ks = lane >> 3, quad = (lane >> 1) & 3, jj = (lane & 1) * 4;
    *(ushort4*)&tile[ks * 512 + (quad * 16 + m16) * 8 + jj] = o;
  }
  __syncthreads();
  uint4* dst = (uint4*)(zbF + (size_t)rg * (16 * DIM));
  const uint4* srcT = (const uint4*)tile;
  dst[threadIdx.x] = srcT[threadIdx.x];
  dst[256 + threadIdx.x] = srcT[256 + threadIdx.x];
}

// ------------------------------------------------ MFMA GEMM + exp + sums
__global__ __launch_bounds__(256, 4) void denom_kernel(
    const unsigned short* __restrict__ zbF, float* __restrict__ denomP,
    float* __restrict__ posv) {
  __shared__ unsigned short As[2][8 * 512];  // 2 x 8 KB (one K=32 A-slice)
  __shared__ unsigned short Bs[2][8 * 512];  // 2 x 8 KB
  __shared__ float red[512];                 // 2 KB reduction buffer

  // XCD-aware bijective swizzle (2080 % 8 == 0): each XCD gets a contiguous
  // run of 260 triangle tiles -> by-panel reuse inside one XCD's L2.
  int t = (blockIdx.x & 7) * (NTRI / 8) + (blockIdx.x >> 3);
  // decode triangle tile id -> (bx, by), bx <= by
  int by = (int)((sqrtf(8.0f * (float)t + 1.0f) - 1.0f) * 0.5f);
  while ((by + 1) * (by + 2) / 2 <= t) ++by;
  while (by * (by + 1) / 2 > t) --by;
  int bx = t - by * (by + 1) / 2;

  const int tid = threadIdx.x;
  const int w = tid >> 6;
  const int lane = tid & 63;
  const int wr = w >> 1, wc = w & 1;  // 2x2 wave grid, 64x64 each
  const int quad = lane >> 4;
  const int m16 = lane & 15;
  const int row0 = bx * BM;
  const int col0 = by * BN;

  // Global staging pointers (per-lane 16 B within each 1 KB chunk).
  const unsigned short* gA = zbF + (size_t)(bx * 8) * 4096 + lane * 8;
  const unsigned short* gB = zbF + (size_t)(by * 8) * 4096 + lane * 8;

  f32x4 acc[4][4];
  #pragma unroll
  for (int i = 0; i < 4; ++i)
    #pragma unroll
    for (int j = 0; j < 4; ++j) {
      f32x4 z4 = {0.f, 0.f, 0.f, 0.f};
      acc[i][j] = z4;
    }

  // stage K=32 slice `ks` into buffer b: 8 chunks of 1 KB each for A and B;
  // wave w handles chunks {w, w+4}. Linear LDS dest = frag layout.
  auto stage = [&](int b, int ks) {
    #pragma unroll
    for (int r = 0; r < 2; ++r) {
      const int c = r * 4 + w;  // rg_local 0..7
      __builtin_amdgcn_global_load_lds(
          (const __attribute__((address_space(1))) unsigned int*)(gA +
              (size_t)c * 4096 + ks * 512),
          (__attribute__((address_space(3))) unsigned int*)&As[b][c * 512],
          16, 0, 0);
      __builtin_amdgcn_global_load_lds(
          (const __attribute__((address_space(1))) unsigned int*)(gB +
              (size_t)c * 4096 + ks * 512),
          (__attribute__((address_space(3))) unsigned int*)&Bs[b][c * 512],
          16, 0, 0);
    }
  };

  auto compute = [&](int b) {
    bf16x8 af[4], bfr[4];
    #pragma unroll
    for (int i = 0; i < 4; ++i)
      af[i] = *(const bf16x8*)&As[b][(wr * 4 + i) * 512 + lane * 8];
    #pragma unroll
    for (int j = 0; j < 4; ++j)
      bfr[j] = *(const bf16x8*)&Bs[b][(wc * 4 + j) * 512 + lane * 8];
    __builtin_amdgcn_s_setprio(1);
    #pragma unroll
    for (int i = 0; i < 4; ++i)
      #pragma unroll
      for (int j = 0; j < 4; ++j)
        acc[i][j] = __builtin_amdgcn_mfma_f32_16x16x32_bf16(
            af[i], bfr[j], acc[i][j], 0, 0, 0);
    __builtin_amdgcn_s_setprio(0);
  };

  stage(0, 0);
  __syncthreads();
  #pragma unroll
  for (int ks = 0; ks < 8; ++ks) {
    if (ks < 7) stage((ks + 1) & 1, ks + 1);
    compute(ks & 1);
    __syncthreads();  // drains stage(ks+1) loads; WAR-protects buf ks&1
  }

  // pos extraction: only tiles with col0 == row0 + NHALF hold pair elements.
  // acc = 2*sim/ln2; reduce applies weight 2*ln2.
  if (col0 - row0 == NHALF) {
    #pragma unroll
    for (int i = 0; i < 4; ++i)
      #pragma unroll
      for (int j = 0; j < 4; ++j) {
        int gcol = col0 + wc * 64 + j * 16 + m16;
        #pragma unroll
        for (int r = 0; r < 4; ++r) {
          int grow = row0 + wr * 64 + i * 16 + quad * 4 + r;
          if (gcol - grow == NHALF) posv[grow] = acc[i][j][r];
        }
      }
  }

  // Epilogue: e = exp2(acc) = exp(2*sim). Diagonal tiles (bx==by, 64 of
  // 2080) pay the grow==gcol compare; off-diagonal tiles skip it.
  float rs[4][4];
  float cs[4] = {0.f, 0.f, 0.f, 0.f};
  #pragma unroll
  for (int i = 0; i < 4; ++i)
    #pragma unroll
    for (int r = 0; r < 4; ++r) rs[i][r] = 0.f;

  if (bx != by) {
    #pragma unroll
    for (int i = 0; i < 4; ++i)
      #pragma unroll
      for (int j = 0; j < 4; ++j)
        #pragma unroll
        for (int r = 0; r < 4; ++r) {
          float e = __builtin_amdgcn_exp2f(acc[i][j][r]);
          rs[i][r] += e;
          cs[j] += e;
        }
  } else {
    #pragma unroll
    for (int i = 0; i < 4; ++i)
      #pragma unroll
      for (int j = 0; j < 4; ++j) {
        int gcol = col0 + wc * 64 + j * 16 + m16;
        #pragma unroll
        for (int r = 0; r < 4; ++r) {
          int grow = row0 + wr * 64 + i * 16 + quad * 4 + r;
          float e =
              (grow == gcol) ? 0.f : __builtin_amdgcn_exp2f(acc[i][j][r]);
          rs[i][r] += e;
          cs[j] += e;
        }
      }
  }

  // rowsum: reduce across the 16 column lanes (same quad)
  #pragma unroll
  for (int i = 0; i < 4; ++i)
    #pragma unroll
    for (int r = 0; r < 4; ++r) {
      float v = rs[i][r];
      v += __shfl_xor(v, 1, 16);
      v += __shfl_xor(v, 2, 16);
      v += __shfl_xor(v, 4, 16);
      v += __shfl_xor(v, 8, 16);
      if (m16 == 0) red[wc * 128 + wr * 64 + i * 16 + quad * 4 + r] = v;
    }
  // colsum: reduce across the 4 quads
  #pragma unroll
  for (int j = 0; j < 4; ++j) {
    float v = cs[j];
    v += __shfl_xor(v, 16, 64);
    v += __shfl_xor(v, 32, 64);
    if (quad == 0) red[256 + wr * 128 + wc * 64 + j * 16 + m16] = v;
  }
  __syncthreads();

  if (tid < 128) {
    denomP[(size_t)by * NROWS + row0 + tid] = red[tid] + red[128 + tid];
  } else if (bx != by) {
    int c = tid - 128;
    denomP[(size_t)bx * NROWS + col0 + c] = red[256 + c] + red[384 + c];
  }
}

// -------------------- denom slots -> -log; + 2*ln2*pos'; atomic into loss
__global__ __launch_bounds__(256) void reduce_kernel(
    const float* __restrict__ denomP, const float* __restrict__ posv,
    float* __restrict__ out) {
  int tid = threadIdx.x;
  int r = blockIdx.x * 256 + tid;  // 32 blocks cover 8192 rows
  float s = 0.f;
  #pragma unroll 8
  for (int b = 0; b < NCB; ++b) s += denomP[(size_t)b * NROWS + r];
  float v = -logf(s);
  // posv = 2*sim/ln2; need 4*sim (covers rows r and r+NHALF) = 2*ln2*posv
  if (r < NHALF) v += 1.38629436112f * posv[r];
  #pragma unroll
  for (int off = 32; off; off >>= 1) v += __shfl_down(v, off, 64);
  __shared__ float s4[4];
  if ((tid & 63) == 0) s4[tid >> 6] = v;
  __syncthreads();
  if (tid == 0)
    atomicAdd(out, (s4[0] + s4[1] + s4[2] + s4[3]) * (1.0f / 8192.0f));
}

extern "C" void kernel_launch(void* const* d_in, const int* in_sizes, int n_in,
                              void* d_out, int out_size, void* d_ws,
                              size_t ws_size, hipStream_t stream) {
  const float* emb_i = (const float*)d_in[0];
  const float* emb_j = (const float*)d_in[1];
  unsigned short* zbF = (unsigned short*)d_ws;           // 4 MB (frag layout)
  float* denomP = (float*)(zbF + (size_t)NROWS * DIM);   // 64*8192 f32 (2 MB)
  float* posv = denomP + (size_t)NCB * NROWS;            // 4096 f32
  float* out = (float*)d_out;

  normalize_kernel<<<NROWS / 16, 256, 0, stream>>>(emb_i, emb_j, zbF, out);
  denom_kernel<<<NTRI, 256, 0, stream>>>(zbF, denomP, posv);
  reduce_kernel<<<NROWS / 256, 256, 0, stream>>>(denomP, posv, out);
}

// Round 6
// 93.777 us; speedup vs baseline: 3.4358x; 1.0083x over previous
//
#include <hip/hip_runtime.h>
#include <math.h>

// NT-Xent (SimCLR) loss. B=4096, D=256, T=0.5.
// R6: R5 + T4 counted-vmcnt pipeline. R5 drained vmcnt(0) at each of its 8
// __syncthreads (stage(ks+1) issued right before the barrier -> ~1 compute
// phase of cover vs 200-400cy L2 latency). Now: prologue stages slices 0,1;
// each phase waits only the OLDEST stage's 4 loads (s_waitcnt vmcnt(4)),
// raw s_barrier (no drain), ds_read+MFMA, raw s_barrier (WAR: all frag
// ds_reads are lgkmcnt-waited before their consuming MFMAs, so buffer reads
// are complete before any wave crosses and restages), then stage(ks+2).
// vmcnt schedule (4 loads/stage/wave, FIFO): in-flight at phase ks wait =
// stages {ks, ks+1} = 8 -> vmcnt(4) retires stage ks; final phase vmcnt(0).
// Everything else unchanged from R5 (frag-native zbF layout, 4 blocks/CU,
// XCD swizzle, exp2 input scaling, setprio).

#define NROWS 8192
#define NHALF 4096
#define DIM   256
#define BM    128
#define BN    128
#define NCB   (NROWS / BN)          // 64 row/col blocks
#define NTRI  (NCB * (NCB + 1) / 2) // 2080 triangle tiles

typedef __attribute__((ext_vector_type(8))) short bf16x8;
typedef __attribute__((ext_vector_type(4))) float f32x4;

static __device__ __forceinline__ unsigned short f2bf(float x) {
  unsigned int u = __float_as_uint(x);
  unsigned int r = (u + 0x7FFFu + ((u >> 16) & 1u)) >> 16;
  return (unsigned short)r;
}

// ---------------- normalize -> fragment-native layout (also zeroes out[0])
__global__ __launch_bounds__(256) void normalize_kernel(
    const float* __restrict__ emb_i, const float* __restrict__ emb_j,
    unsigned short* __restrict__ zbF, float* __restrict__ out) {
  __shared__ unsigned short tile[16 * DIM];  // 8 KB
  if (blockIdx.x == 0 && threadIdx.x == 0) out[0] = 0.f;
  const int w = threadIdx.x >> 6, lane = threadIdx.x & 63;
  const int rg = blockIdx.x;
  #pragma unroll
  for (int rr = 0; rr < 4; ++rr) {
    const int m16 = w * 4 + rr;
    const int row = rg * 16 + m16;
    const float* src = (row < NHALF) ? (emb_i + (size_t)row * DIM)
                                     : (emb_j + (size_t)(row - NHALF) * DIM);
    float4 v = ((const float4*)src)[lane];
    float ss = v.x * v.x + v.y * v.y + v.z * v.z + v.w * v.w;
    #pragma unroll
    for (int off = 32; off; off >>= 1) ss += __shfl_down(ss, off, 64);
    float total = __shfl(ss, 0, 64);
    // sqrt(2/ln2): acc = 2*sim/ln2, so epilogue is exp2(acc) directly.
    float inv = 1.69870077f / fmaxf(sqrtf(total), 1e-12f);
    ushort4 o;
    o.x = f2bf(v.x * inv); o.y = f2bf(v.y * inv);
    o.z = f2bf(v.z * inv); o.w = f2bf(v.w * inv);
    // k = lane*4 -> ks = lane>>3, quad = (lane>>1)&3, j = (lane&1)*4
    const int ks = lane >> 3, quad = (lane >> 1) & 3, jj = (lane & 1) * 4;
    *(ushort4*)&tile[ks * 512 + (quad * 16 + m16) * 8 + jj] = o;
  }
  __syncthreads();
  uint4* dst = (uint4*)(zbF + (size_t)rg * (16 * DIM));
  const uint4* srcT = (const uint4*)tile;
  dst[threadIdx.x] = srcT[threadIdx.x];
  dst[256 + threadIdx.x] = srcT[256 + threadIdx.x];
}

// ------------------------------------------------ MFMA GEMM + exp + sums
__global__ __launch_bounds__(256, 4) void denom_kernel(
    const unsigned short* __restrict__ zbF, float* __restrict__ denomP,
    float* __restrict__ posv) {
  __shared__ unsigned short As[2][8 * 512];  // 2 x 8 KB (one K=32 A-slice)
  __shared__ unsigned short Bs[2][8 * 512];  // 2 x 8 KB
  __shared__ float red[512];                 // 2 KB reduction buffer

  // XCD-aware bijective swizzle (2080 % 8 == 0): each XCD gets a contiguous
  // run of 260 triangle tiles -> by-panel reuse inside one XCD's L2.
  int t = (blockIdx.x & 7) * (NTRI / 8) + (blockIdx.x >> 3);
  // decode triangle tile id -> (bx, by), bx <= by
  int by = (int)((sqrtf(8.0f * (float)t + 1.0f) - 1.0f) * 0.5f);
  while ((by + 1) * (by + 2) / 2 <= t) ++by;
  while (by * (by + 1) / 2 > t) --by;
  int bx = t - by * (by + 1) / 2;

  const int tid = threadIdx.x;
  const int w = tid >> 6;
  const int lane = tid & 63;
  const int wr = w >> 1, wc = w & 1;  // 2x2 wave grid, 64x64 each
  const int quad = lane >> 4;
  const int m16 = lane & 15;
  const int row0 = bx * BM;
  const int col0 = by * BN;

  // Global staging pointers (per-lane 16 B within each 1 KB chunk).
  const unsigned short* gA = zbF + (size_t)(bx * 8) * 4096 + lane * 8;
  const unsigned short* gB = zbF + (size_t)(by * 8) * 4096 + lane * 8;

  f32x4 acc[4][4];
  #pragma unroll
  for (int i = 0; i < 4; ++i)
    #pragma unroll
    for (int j = 0; j < 4; ++j) {
      f32x4 z4 = {0.f, 0.f, 0.f, 0.f};
      acc[i][j] = z4;
    }

  // stage K=32 slice `ks` into buffer b: 8 chunks of 1 KB each for A and B;
  // wave w handles chunks {w, w+4}. Linear LDS dest = frag layout.
  // 4 loads/wave, issued in FIFO order (A0,B0,A1,B1) -> vmcnt counts stages.
  auto stage = [&](int b, int ks) {
    #pragma unroll
    for (int r = 0; r < 2; ++r) {
      const int c = r * 4 + w;  // rg_local 0..7
      __builtin_amdgcn_global_load_lds(
          (const __attribute__((address_space(1))) unsigned int*)(gA +
              (size_t)c * 4096 + ks * 512),
          (__attribute__((address_space(3))) unsigned int*)&As[b][c * 512],
          16, 0, 0);
      __builtin_amdgcn_global_load_lds(
          (const __attribute__((address_space(1))) unsigned int*)(gB +
              (size_t)c * 4096 + ks * 512),
          (__attribute__((address_space(3))) unsigned int*)&Bs[b][c * 512],
          16, 0, 0);
    }
  };

  auto compute = [&](int b) {
    bf16x8 af[4], bfr[4];
    #pragma unroll
    for (int i = 0; i < 4; ++i)
      af[i] = *(const bf16x8*)&As[b][(wr * 4 + i) * 512 + lane * 8];
    #pragma unroll
    for (int j = 0; j < 4; ++j)
      bfr[j] = *(const bf16x8*)&Bs[b][(wc * 4 + j) * 512 + lane * 8];
    __builtin_amdgcn_s_setprio(1);
    #pragma unroll
    for (int i = 0; i < 4; ++i)
      #pragma unroll
      for (int j = 0; j < 4; ++j)
        acc[i][j] = __builtin_amdgcn_mfma_f32_16x16x32_bf16(
            af[i], bfr[j], acc[i][j], 0, 0, 0);
    __builtin_amdgcn_s_setprio(0);
  };

  // ---- T4 counted-vmcnt 2-deep pipeline (8 K=32 phases) ----
  stage(0, 0);
  stage(1, 1);
  // PHASE(ks): wait oldest stage's 4 loads; data barrier; compute; WAR
  // barrier; restage. asm("" ::: "memory") after the data barrier stops the
  // compiler hoisting this wave's ds_reads above the barrier (the staged
  // data it reads was written under OTHER waves' vmcnt).
#define PHASE(ks, NWAIT, DO_STAGE)                                  \
  do {                                                              \
    asm volatile("s_waitcnt vmcnt(" #NWAIT ")" ::: "memory");       \
    __builtin_amdgcn_s_barrier();                                   \
    asm volatile("" ::: "memory");                                  \
    compute((ks) & 1);                                              \
    __builtin_amdgcn_s_barrier();                                   \
    asm volatile("" ::: "memory");                                  \
    if (DO_STAGE) stage((ks) & 1, (ks) + 2);                        \
  } while (0)

  PHASE(0, 4, 1);
  PHASE(1, 4, 1);
  PHASE(2, 4, 1);
  PHASE(3, 4, 1);
  PHASE(4, 4, 1);
  PHASE(5, 4, 1);
  PHASE(6, 4, 0);
  PHASE(7, 0, 0);
#undef PHASE

  // pos extraction: only tiles with col0 == row0 + NHALF hold pair elements.
  // acc = 2*sim/ln2; reduce applies weight 2*ln2.
  if (col0 - row0 == NHALF) {
    #pragma unroll
    for (int i = 0; i < 4; ++i)
      #pragma unroll
      for (int j = 0; j < 4; ++j) {
        int gcol = col0 + wc * 64 + j * 16 + m16;
        #pragma unroll
        for (int r = 0; r < 4; ++r) {
          int grow = row0 + wr * 64 + i * 16 + quad * 4 + r;
          if (gcol - grow == NHALF) posv[grow] = acc[i][j][r];
        }
      }
  }

  // Epilogue: e = exp2(acc) = exp(2*sim). Diagonal tiles (bx==by, 64 of
  // 2080) pay the grow==gcol compare; off-diagonal tiles skip it.
  float rs[4][4];
  float cs[4] = {0.f, 0.f, 0.f, 0.f};
  #pragma unroll
  for (int i = 0; i < 4; ++i)
    #pragma unroll
    for (int r = 0; r < 4; ++r) rs[i][r] = 0.f;

  if (bx != by) {
    #pragma unroll
    for (int i = 0; i < 4; ++i)
      #pragma unroll
      for (int j = 0; j < 4; ++j)
        #pragma unroll
        for (int r = 0; r < 4; ++r) {
          float e = __builtin_amdgcn_exp2f(acc[i][j][r]);
          rs[i][r] += e;
          cs[j] += e;
        }
  } else {
    #pragma unroll
    for (int i = 0; i < 4; ++i)
      #pragma unroll
      for (int j = 0; j < 4; ++j) {
        int gcol = col0 + wc * 64 + j * 16 + m16;
        #pragma unroll
        for (int r = 0; r < 4; ++r) {
          int grow = row0 + wr * 64 + i * 16 + quad * 4 + r;
          float e =
              (grow == gcol) ? 0.f : __builtin_amdgcn_exp2f(acc[i][j][r]);
          rs[i][r] += e;
          cs[j] += e;
        }
      }
  }

  // rowsum: reduce across the 16 column lanes (same quad)
  #pragma unroll
  for (int i = 0; i < 4; ++i)
    #pragma unroll
    for (int r = 0; r < 4; ++r) {
      float v = rs[i][r];
      v += __shfl_xor(v, 1, 16);
      v += __shfl_xor(v, 2, 16);
      v += __shfl_xor(v, 4, 16);
      v += __shfl_xor(v, 8, 16);
      if (m16 == 0) red[wc * 128 + wr * 64 + i * 16 + quad * 4 + r] = v;
    }
  // colsum: reduce across the 4 quads
  #pragma unroll
  for (int j = 0; j < 4; ++j) {
    float v = cs[j];
    v += __shfl_xor(v, 16, 64);
    v += __shfl_xor(v, 32, 64);
    if (quad == 0) red[256 + wr * 128 + wc * 64 + j * 16 + m16] = v;
  }
  __syncthreads();

  if (tid < 128) {
    denomP[(size_t)by * NROWS + row0 + tid] = red[tid] + red[128 + tid];
  } else if (bx != by) {
    int c = tid - 128;
    denomP[(size_t)bx * NROWS + col0 + c] = red[256 + c] + red[384 + c];
  }
}

// -------------------- denom slots -> -log; + 2*ln2*pos'; atomic into loss
__global__ __launch_bounds__(256) void reduce_kernel(
    const float* __restrict__ denomP, const float* __restrict__ posv,
    float* __restrict__ out) {
  int tid = threadIdx.x;
  int r = blockIdx.x * 256 + tid;  // 32 blocks cover 8192 rows
  float s = 0.f;
  #pragma unroll 8
  for (int b = 0; b < NCB; ++b) s += denomP[(size_t)b * NROWS + r];
  float v = -logf(s);
  // posv = 2*sim/ln2; need 4*sim (covers rows r and r+NHALF) = 2*ln2*posv
  if (r < NHALF) v += 1.38629436112f * posv[r];
  #pragma unroll
  for (int off = 32; off; off >>= 1) v += __shfl_down(v, off, 64);
  __shared__ float s4[4];
  if ((tid & 63) == 0) s4[tid >> 6] = v;
  __syncthreads();
  if (tid == 0)
    atomicAdd(out, (s4[0] + s4[1] + s4[2] + s4[3]) * (1.0f / 8192.0f));
}

extern "C" void kernel_launch(void* const* d_in, const int* in_sizes, int n_in,
                              void* d_out, int out_size, void* d_ws,
                              size_t ws_size, hipStream_t stream) {
  const float* emb_i = (const float*)d_in[0];
  const float* emb_j = (const float*)d_in[1];
  unsigned short* zbF = (unsigned short*)d_ws;           // 4 MB (frag layout)
  float* denomP = (float*)(zbF + (size_t)NROWS * DIM);   // 64*8192 f32 (2 MB)
  float* posv = denomP + (size_t)NCB * NROWS;            // 4096 f32
  float* out = (float*)d_out;

  normalize_kernel<<<NROWS / 16, 256, 0, stream>>>(emb_i, emb_j, zbF, out);
  denom_kernel<<<NTRI, 256, 0, stream>>>(zbF, denomP, posv);
  reduce_kernel<<<NROWS / 256, 256, 0, stream>>>(denomP, posv, out);
}